// Round 12
// baseline (640.925 us; speedup 1.0000x reference)
//
#include <hip/hip_runtime.h>
#include <hip/hip_bf16.h>

// FAVOR+ attention, MI355X. Round 12: mm_k -> m97-style global_load_lds GEMM.
//  - mm_k: 128^2 tile, BK=32, linear LDS (8KB+8KB), async global->LDS via
//    __builtin_amdgcn_global_load_lds width=16, 2 barriers/K-step (m97
//    structure, 874-912 TF documented). XCD swizzle kept.
//  - outchunk / kvstate / scan / convs: byte-identical to validated R11.
//
// Workspace (bytes), total 211,845,120 (~202 MB):
//   v      bf16 [64bh][4096][64]   @ 0            (32 MB)
//   q      bf16                    @ 33,554,432   (32 MB)
//   k      bf16                    @ 67,108,864   (32 MB)
//   xb     bf16 [16384][1024]      @ 100,663,296  (32 MB) -- ALIASED attn
//   stateb bf16 [64bh][32][16384]  @ 134,217,728  (64 MB)
//   ksum   f32  [64bh][32][256]    @ 201,326,592  (2 MB)
//   Wt     bf16 4x[1024][1024]     @ 203,423,744  (8 MB)
//   omb    bf16 [256][64]          @ 211,812,352  (32 KB)

#define B_ 4
#define H_ 16
#define L_ 4096
#define D_ 64
#define M_ 256
#define DM_ 1024
#define BH_ 64
#define NSC 32            // superchunks per bh (SC = 128 tokens)

typedef unsigned int u32;
typedef unsigned short u16;
typedef __attribute__((ext_vector_type(8))) short bf16x8;
typedef __attribute__((ext_vector_type(4))) float f32x4;

static __device__ __forceinline__ float bf2f(u16 u) {
  return __uint_as_float(((u32)u) << 16);
}
static __device__ __forceinline__ u16 f2bf(float f) {
  u32 x = __float_as_uint(f);
  return (u16)((x + 0x7fffu + ((x >> 16) & 1u)) >> 16);   // RNE
}
#define MFMA16(a, b, c) __builtin_amdgcn_mfma_f32_16x16x32_bf16((a), (b), (c), 0, 0, 0)

#define GLOAD_LDS16(gsrc, ldst)                                                \
  __builtin_amdgcn_global_load_lds(                                            \
      (const __attribute__((address_space(1))) void*)(gsrc),                   \
      (__attribute__((address_space(3))) void*)(ldst), 16, 0, 0)

// ---------------- converters ----------------------------------------------
__global__ __launch_bounds__(256) void convx_k(const float* __restrict__ x,
                                               u16* __restrict__ xb) {
  const int i = blockIdx.x * 256 + threadIdx.x;
  float4 f = ((const float4*)x)[i];
  ushort4 u;
  u.x = f2bf(f.x); u.y = f2bf(f.y); u.z = f2bf(f.z); u.w = f2bf(f.w);
  ((ushort4*)xb)[i] = u;
}

__global__ __launch_bounds__(256) void convw_k(
    const float* __restrict__ W0, const float* __restrict__ W1,
    const float* __restrict__ W2, const float* __restrict__ W3,
    u16* __restrict__ out) {
  __shared__ u16 tt[64][66];
  const int z = blockIdx.z;
  const float* W = (z == 0) ? W0 : (z == 1) ? W1 : (z == 2) ? W2 : W3;
  u16* o = out + (size_t)z * 1048576ull;
  const int k0 = blockIdx.y * 64, n0 = blockIdx.x * 64;
  const int r = threadIdx.x >> 4, c4 = (threadIdx.x & 15) << 2;
  for (int rr = r; rr < 64; rr += 16) {
    float4 w4 = *(const float4*)(W + (size_t)(k0 + rr) * DM_ + n0 + c4);
    tt[c4 + 0][rr] = f2bf(w4.x);
    tt[c4 + 1][rr] = f2bf(w4.y);
    tt[c4 + 2][rr] = f2bf(w4.z);
    tt[c4 + 3][rr] = f2bf(w4.w);
  }
  __syncthreads();
  for (int rr = r; rr < 64; rr += 16) {
    ushort4 u4;
    u4.x = tt[rr][c4 + 0];
    u4.y = tt[rr][c4 + 1];
    u4.z = tt[rr][c4 + 2];
    u4.w = tt[rr][c4 + 3];
    *(ushort4*)(o + (size_t)(n0 + rr) * DM_ + k0 + c4) = u4;
  }
}

__global__ __launch_bounds__(256) void convom_k(const float* __restrict__ om,
                                                u16* __restrict__ omb) {
  const int i = blockIdx.x * 256 + threadIdx.x;
  omb[i] = f2bf(om[i] * 0.35355339059327373f);       // fold 64^-0.25
}

// ---------------- bf16 MFMA GEMM: m97 structure (global_load_lds) ----------
// 128x128 tile, BK=32, linear LDS, async staging, 2 barriers/K-step.
// MODE 0: bf16 head layout [bh][l][64]; MODE 1: f32 row-major [m][1024].
template<int MODE>
__global__ __launch_bounds__(256) void mm_k(
    const u16* __restrict__ A, const u16* __restrict__ Bt,
    const float* __restrict__ bias, void* __restrict__ outp) {
  __shared__ u16 sAl[128 * 32];   // 8 KB linear [row][k] k-stride 32
  __shared__ u16 sBl[128 * 32];   // 8 KB linear
  const int tid = threadIdx.x, lane = tid & 63, w = tid >> 6;
  const int fr = lane & 15, fg = lane >> 4;
  const int wr = w >> 1, wc = w & 1;
  const int lb = ((blockIdx.x & 7) << 7) | (blockIdx.x >> 3);   // XCD swizzle
  const int m0 = (lb >> 3) * 128, n0 = (lb & 7) * 128;
  // staging: seg = w*2+p in [0,8); LDS bytes [seg*1024, +1024); lane i -> +i*16
  // row = seg*16 + (lane>>2), col-byte = (lane&3)*16
  const int srow = lane >> 2;
  const int scolb = (lane & 3) * 16;
  f32x4 acc[4][4] = {};
  for (int k0 = 0; k0 < DM_; k0 += 32) {
    __syncthreads();   // WAR: prior K-step's ds_reads complete
#pragma unroll
    for (int p = 0; p < 2; ++p) {
      const int seg = w * 2 + p;
      const int row = seg * 16 + srow;
      const char* ga = (const char*)A  + (size_t)(m0 + row) * (DM_ * 2) + k0 * 2 + scolb;
      const char* gb = (const char*)Bt + (size_t)(n0 + row) * (DM_ * 2) + k0 * 2 + scolb;
      GLOAD_LDS16(ga, (char*)sAl + seg * 1024);
      GLOAD_LDS16(gb, (char*)sBl + seg * 1024);
    }
    __syncthreads();   // RAW: compiler drains vmcnt(0) before barrier
    bf16x8 af[4], bf[4];
#pragma unroll
    for (int i = 0; i < 4; ++i)
      af[i] = *(const bf16x8*)&sAl[(wr * 64 + i * 16 + fr) * 32 + fg * 8];
#pragma unroll
    for (int j = 0; j < 4; ++j)
      bf[j] = *(const bf16x8*)&sBl[(wc * 64 + j * 16 + fr) * 32 + fg * 8];
#pragma unroll
    for (int i = 0; i < 4; ++i)
#pragma unroll
      for (int j = 0; j < 4; ++j)
        acc[i][j] = MFMA16(af[i], bf[j], acc[i][j]);
  }
  const int m_blk = m0 + wr * 64, n_blk = n0 + wc * 64;
#pragma unroll
  for (int j = 0; j < 4; ++j) {
    const int n = n_blk + j * 16 + fr;
    const float bi = bias[n];
    const int h = n >> 6, d = n & 63;
#pragma unroll
    for (int i = 0; i < 4; ++i) {
#pragma unroll
      for (int r = 0; r < 4; ++r) {
        const int m = m_blk + i * 16 + fg * 4 + r;
        const float val = acc[i][j][r] + bi;
        if (MODE == 0) {
          const int b = m >> 12, l = m & 4095;
          ((u16*)outp)[((size_t)(b * H_ + h) * L_ + l) * D_ + d] = f2bf(val);
        } else {
          ((float*)outp)[(size_t)m * DM_ + n] = val;
        }
      }
    }
  }
}

// ---------------- shared: LDS sumsq (kvstate, validated) -------------------
static __device__ __forceinline__ void sumsq_tile(
    const u16* __restrict__ xg, float (*ssq)[4], float* __restrict__ nh, int tid) {
  const int t = tid >> 2, qt = tid & 3;
  const u16* xp = xg + t * 64 + qt * 16;
  float s = 0.f;
#pragma unroll
  for (int jj = 0; jj < 2; ++jj) {
    bf16x8 xv = *(const bf16x8*)(xp + jj * 8);
#pragma unroll
    for (int e = 0; e < 8; ++e) { const float f = bf2f((u16)xv[e]); s += f * f; }
  }
  ssq[t][qt] = s;
  __syncthreads();
  if (tid < 64)
    nh[tid] = 0.0625f * (ssq[tid][0] + ssq[tid][1] + ssq[tid][2] + ssq[tid][3]);
  __syncthreads();
}

// ---------------- kvstate (MFMA, SC=128): bf16 state + f32 ksum ------------
__global__ __launch_bounds__(256) void kvstate_k(
    const u16* __restrict__ k, const u16* __restrict__ v,
    const u16* __restrict__ omb, u16* __restrict__ stateb,
    float* __restrict__ ksum) {
  __shared__ u16 sPhi[256][72];
  __shared__ u16 sVt[64][72];
  __shared__ float ssq[64][4];
  __shared__ float nh[64];
  const int tid = threadIdx.x, lane = tid & 63, w = tid >> 6;
  const int fr = lane & 15, fg = lane >> 4;
  const int sc = blockIdx.x, bh = blockIdx.y;
  const size_t base_l = (size_t)bh * L_ + (size_t)sc * 128;

  bf16x8 ones;
#pragma unroll
  for (int e = 0; e < 8; ++e) ones[e] = (short)0x3F80;

  f32x4 kvacc[4][4] = {};
  f32x4 ksacc[4] = {};

  for (int sub = 0; sub < 2; ++sub) {
    const size_t tl = base_l + sub * 64;
    const u16* kg = k + tl * 64;
    __syncthreads();
    {
      const u16* vp = v + (tl + lane) * 64 + w * 16;
      bf16x8 v0 = *(const bf16x8*)(vp);
      bf16x8 v1 = *(const bf16x8*)(vp + 8);
#pragma unroll
      for (int e = 0; e < 8; ++e) sVt[w * 16 + e][lane] = (u16)v0[e];
#pragma unroll
      for (int e = 0; e < 8; ++e) sVt[w * 16 + 8 + e][lane] = (u16)v1[e];
    }
    sumsq_tile(kg, ssq, nh, tid);
#pragma unroll
    for (int mi = 0; mi < 4; ++mi) {
      const int m0 = (w << 6) + mi * 16;
      const bf16x8 a0 = *(const bf16x8*)(omb + (m0 + fr) * 64 + fg * 8);
      const bf16x8 a1 = *(const bf16x8*)(omb + (m0 + fr) * 64 + 32 + fg * 8);
#pragma unroll
      for (int tt = 0; tt < 4; ++tt) {
        const bf16x8 b0 = *(const bf16x8*)(kg + (tt * 16 + fr) * 64 + fg * 8);
        const bf16x8 b1 = *(const bf16x8*)(kg + (tt * 16 + fr) * 64 + 32 + fg * 8);
        f32x4 acc = {0.f, 0.f, 0.f, 0.f};
        acc = MFMA16(a0, b0, acc);
        acc = MFMA16(a1, b1, acc);
        const float nhv = nh[tt * 16 + fr];
#pragma unroll
        for (int r = 0; r < 4; ++r)
          sPhi[m0 + fg * 4 + r][tt * 16 + fr] = f2bf(__expf(acc[r] - nhv) * 0.0625f);
      }
    }
    __syncthreads();
#pragma unroll
    for (int mi = 0; mi < 4; ++mi) {
      const int m0 = (w << 6) + mi * 16;
      const bf16x8 pb0 = *(const bf16x8*)&sPhi[m0 + fr][fg * 8];
      const bf16x8 pb1 = *(const bf16x8*)&sPhi[m0 + fr][32 + fg * 8];
      ksacc[mi] = MFMA16(pb0, ones, ksacc[mi]);
      ksacc[mi] = MFMA16(pb1, ones, ksacc[mi]);
#pragma unroll
      for (int dj = 0; dj < 4; ++dj) {
        const bf16x8 va0 = *(const bf16x8*)&sVt[dj * 16 + fr][fg * 8];
        const bf16x8 va1 = *(const bf16x8*)&sVt[dj * 16 + fr][32 + fg * 8];
        kvacc[mi][dj] = MFMA16(va0, pb0, kvacc[mi][dj]);
        kvacc[mi][dj] = MFMA16(va1, pb1, kvacc[mi][dj]);
      }
    }
  }
  // state bf16 [d][m]; ksum f32
  u16* stb = stateb + (size_t)(bh * NSC + sc) * (M_ * D_);
  float* ksp = ksum + (size_t)(bh * NSC + sc) * M_;
#pragma unroll
  for (int mi = 0; mi < 4; ++mi) {
    const int m = (w << 6) + mi * 16 + fr;
#pragma unroll
    for (int dj = 0; dj < 4; ++dj)
#pragma unroll
      for (int r = 0; r < 4; ++r)
        stb[(size_t)(dj * 16 + fg * 4 + r) * M_ + m] = f2bf(kvacc[mi][dj][r]);
    if (fr == 0) {
#pragma unroll
      for (int r = 0; r < 4; ++r)
        ksp[(w << 6) + mi * 16 + fg * 4 + r] = ksacc[mi][r];
    }
  }
}

// ---------------- exclusive prefix over superchunks (bf16 state) -----------
__global__ __launch_bounds__(256) void scan_k(u16* __restrict__ stateb,
                                              float* __restrict__ ksum) {
  const int bh = blockIdx.y;
  u16* sb = stateb + (size_t)bh * NSC * (M_ * D_);
  const int base = blockIdx.x * 2048 + threadIdx.x * 8;
  float run[8] = {};
  for (int cc = 0; cc < NSC; ++cc) {
    u16* st = sb + (size_t)cc * (M_ * D_) + base;
    ushort4 t0 = *(ushort4*)st;
    ushort4 t1 = *(ushort4*)(st + 4);
    ushort4 w0, w1;
    w0.x = f2bf(run[0]); w0.y = f2bf(run[1]); w0.z = f2bf(run[2]); w0.w = f2bf(run[3]);
    w1.x = f2bf(run[4]); w1.y = f2bf(run[5]); w1.z = f2bf(run[6]); w1.w = f2bf(run[7]);
    *(ushort4*)st = w0;
    *(ushort4*)(st + 4) = w1;
    run[0] += bf2f(t0.x); run[1] += bf2f(t0.y); run[2] += bf2f(t0.z); run[3] += bf2f(t0.w);
    run[4] += bf2f(t1.x); run[5] += bf2f(t1.y); run[6] += bf2f(t1.z); run[7] += bf2f(t1.w);
  }
  if (blockIdx.x == 0) {           // ksum f32 in-place exclusive prefix
    float rk = 0.f;
    for (int cc = 0; cc < NSC; ++cc) {
      float* p = ksum + (size_t)(bh * NSC + cc) * M_ + threadIdx.x;
      const float t = *p;
      *p = rk;
      rk += t;
    }
  }
}

// ---------------- outchunk helpers (validated) -----------------------------
// per-wave sumsq via shfl; band index wb in [0,4)
static __device__ __forceinline__ void sumsq_wave(
    const u16* __restrict__ xg, int wb, int lane, float* nhv) {
  const u16* xp = xg + (wb * 16 + (lane & 15)) * 64;
  float s = 0.f;
#pragma unroll
  for (int p = 0; p < 8; ++p) {
    bf16x8 xv = *(const bf16x8*)(xp + p * 8);
#pragma unroll
    for (int e = 0; e < 8; ++e) { const float f = bf2f((u16)xv[e]); s += f * f; }
  }
  s *= 0.0625f;
  const int fg = lane >> 4;
#pragma unroll
  for (int r = 0; r < 4; ++r) nhv[r] = __shfl(s, fg * 4 + r, 64);
}

// phi quadrant: writes ONLY rows of band wb (wb*16..wb*16+15)
static __device__ __forceinline__ void phi_quad(
    const u16* __restrict__ xg, const u16* __restrict__ ombq,
    u16* __restrict__ dst, int dstride, const float* nhv,
    int wb, int lane) {
  const int fr = lane & 15, fg = lane >> 4;
  const int tband = wb * 16;
  const bf16x8 a0 = *(const bf16x8*)(xg + (tband + fr) * 64 + fg * 8);
  const bf16x8 a1 = *(const bf16x8*)(xg + (tband + fr) * 64 + 32 + fg * 8);
#pragma unroll
  for (int j = 0; j < 4; ++j) {
    const bf16x8 b0 = *(const bf16x8*)(ombq + (j * 16 + fr) * 64 + fg * 8);
    const bf16x8 b1 = *(const bf16x8*)(ombq + (j * 16 + fr) * 64 + 32 + fg * 8);
    f32x4 acc = {0.f, 0.f, 0.f, 0.f};
    acc = MFMA16(a0, b0, acc);
    acc = MFMA16(a1, b1, acc);
#pragma unroll
    for (int r = 0; r < 4; ++r) {
      const int t = tband + fg * 4 + r;
      dst[t * dstride + j * 16 + fr] = f2bf(__expf(acc[r] - nhv[r]) * 0.0625f);
    }
  }
}

// ---------------- outchunk: merged superchunk, 512 threads (R11) -----------
__global__ __launch_bounds__(512) void outchunk_k(
    const u16* __restrict__ q, const u16* __restrict__ kk,
    const u16* __restrict__ v, const u16* __restrict__ omb,
    const u16* __restrict__ stateb, const float* __restrict__ ksum,
    u16* __restrict__ attn) {
  __shared__ u16 sA[2][64][264];  // Qp per half            67,584 B
  __shared__ u16 sK0[64][72];     // phi(k) ping / h0 S      9,216 B
  __shared__ u16 sK1[64][72];     // phi(k) pong / h1 S      9,216 B
  __shared__ u16 sB1[64][72];     // vT                      9,216 B
  __shared__ float ksum_l[256];   //  1,024 B   total 96,256 B -> 1/CU
  const int tid = threadIdx.x, lane = tid & 63, w = tid >> 6;
  const int h = w >> 2, wl = w & 3;
  const int fr = lane & 15, fg = lane >> 4;
  const int bh = blockIdx.x >> 5, sc = blockIdx.x & 31;
  const size_t tokq = (size_t)bh * L_ + (size_t)sc * 128 + (size_t)h * 64;
  const u16* qg = q + tokq * 64;
  const u16* stgb = stateb + (size_t)(bh * NSC + sc) * (M_ * D_);   // [d][m]
  const float* ksg = ksum + (size_t)(bh * NSC + sc) * M_;

  if (tid < 256) ksum_l[tid] = ksg[tid];

  // phi(q) -> sA[h]: own-band writes, later readers same-wave own-band.
  float nhq[4];
  sumsq_wave(qg, wl, lane, nhq);
#pragma unroll 1
  for (int mq = 0; mq < 4; ++mq)
    phi_quad(qg, omb + mq * 4096, &sA[h][0][mq * 64], 264, nhq, wl, lane);
  __syncthreads();   // BAR P: ksum_l visibility

  // den-ksum (R10-validated): lane (fr,fg) -> token wl*16+fr, m-quarter fg
  float denk = 0.f;
#pragma unroll
  for (int g8 = 0; g8 < 8; ++g8) {
    bf16x8 qv = *(const bf16x8*)&sA[h][wl * 16 + fr][fg * 64 + g8 * 8];
#pragma unroll
    for (int e = 0; e < 8; ++e)
      denk += bf2f((u16)qv[e]) * ksum_l[fg * 64 + g8 * 8 + e];
  }
  denk += __shfl_xor(denk, 16, 64);
  denk += __shfl_xor(denk, 32, 64);

  // cross term: Qp @ KVex, B-frags direct from global bf16 [d][m]
  f32x4 oacc[4] = {};
  __builtin_amdgcn_s_setprio(1);
#pragma unroll
  for (int mq = 0; mq < 4; ++mq) {
    const bf16x8 a0 = *(const bf16x8*)&sA[h][wl * 16 + fr][mq * 64 + fg * 8];
    const bf16x8 a1 = *(const bf16x8*)&sA[h][wl * 16 + fr][mq * 64 + 32 + fg * 8];
#pragma unroll
    for (int j = 0; j < 4; ++j) {
      const bf16x8 b0 = *(const bf16x8*)(stgb + (size_t)(j * 16 + fr) * M_ + mq * 64 + fg * 8);
      const bf16x8 b1 = *(const bf16x8*)(stgb + (size_t)(j * 16 + fr) * M_ + mq * 64 + 32 + fg * 8);
      oacc[j] = MFMA16(a0, b0, oacc[j]);
      oacc[j] = MFMA16(a1, b1, oacc[j]);
    }
  }
  __builtin_amdgcn_s_setprio(0);

  // ---- source chunks s=0,1. phi(k) quadrant mq produced by half (mq&1);
  //      half0 participates in S/SV only at s=0; diag mask when s==h.
  float dS[4] = {0.f, 0.f, 0.f, 0.f};
#pragma unroll 1
  for (int s = 0; s < 2; ++s) {
    const size_t ktok = (size_t)bh * L_ + (size_t)sc * 128 + (size_t)s * 64;
    const u16* kg = kk + ktok * 64;
    const bool part = (h == 1) || (s == 0);
    const bool diag = (s == h);
    float nhk[4];
    sumsq_wave(kg, wl, lane, nhk);
    f32x4 sacc[4] = {};
    if (h == 0)   // quadrant 0 producer (sK0 WAR: prior reads were same-wave)
      phi_quad(kg, omb, &sK0[0][0], 72, nhk, wl, lane);
    __syncthreads();   // BAR A: quadrant 0 ready; fences prev-phase sB1/sK1 readers
#pragma unroll 1
    for (int mq = 0; mq < 4; ++mq) {
      u16* nxt = ((mq & 1) == 0) ? &sK1[0][0] : &sK0[0][0];
      const u16 (*cur)[72] = ((mq & 1) == 0) ? sK0 : sK1;
      if (mq < 3 && h == ((mq + 1) & 1))
        phi_quad(kg, omb + (mq + 1) * 4096, nxt, 72, nhk, wl, lane);
      if (part) {
        const bf16x8 a0 = *(const bf16x8*)&sA[h][wl * 16 + fr][mq * 64 + fg * 8];
        const bf16x8 a1 = *(const bf16x8*)&sA[h][wl * 16 + fr][mq * 64 + 32 + fg * 8];
        __builtin_amdgcn_s_setprio(1);
#pragma unroll
        for (int j = 0; j < 4; ++j) {
          const bf16x8 b0 = *(const bf16x8*)&cur[j * 16 + fr][fg * 8];
          const bf16x8 b1 = *(const bf16x8*)&cur[j * 16 + fr][32 + fg * 8];
          sacc[j] = MFMA16(a0, b0, sacc[j]);
          sacc[j] = MFMA16(a1, b1, sacc[j]);
        }
        __builtin_amdgcn_s_setprio(0);
      }
      __syncthreads();   // quadrant BAR: nxt ready / WAR fence on cur
    }
    // S write (half h into its own buffer; own-band rows), dS from rounded val
    u16 (*sS)[72] = (h == 0) ? sK0 : sK1;
    if (part) {
#pragma unroll
      for (int j = 0; j < 4; ++j)
#pragma unroll
        for (int r = 0; r < 4; ++r) {
          const int ss = j * 16 + fr, t = wl * 16 + fg * 4 + r;
          float val = sacc[j][r];
          if (diag && ss > t) val = 0.f;
          const u16 vb = f2bf(val);
          sS[t][ss] = vb;
          dS[r] += bf2f(vb);
        }
    }
    if (h == 0) {  // vT staging (bands wl*16; prior readers fenced by BAR A)
      const u16* vp = v + (ktok + lane) * 64 + wl * 16;
      bf16x8 v0 = *(const bf16x8*)(vp);
      bf16x8 v1 = *(const bf16x8*)(vp + 8);
#pragma unroll
      for (int e = 0; e < 8; ++e) sB1[wl * 16 + e][lane] = (u16)v0[e];
#pragma unroll
      for (int e = 0; e < 8; ++e) sB1[wl * 16 + 8 + e][lane] = (u16)v1[e];
    }
    __syncthreads();   // BAR F: S buffers + vT visible
    if (part) {        // S @ V (A: own buffer own band; B: sB1 cross-band)
      const bf16x8 a0 = *(const bf16x8*)&sS[wl * 16 + fr][fg * 8];
      const bf16x8 a1 = *(const bf16x8*)&sS[wl * 16 + fr][32 + fg * 8];
      __builtin_amdgcn_s_setprio(1);
#pragma unroll
      for (int j = 0; j < 4; ++j) {
        const bf16x8 b0 = *(const bf16x8*)&sB1[j * 16 + fr][fg * 8];
        const bf16x8 b1 = *(const bf16x8*)&sB1[j * 16 + fr][32 + fg * 8];
        oacc[j] = MFMA16(a0, b0, oacc[j]);
        oacc[j] = MFMA16(a1, b1, oacc[j]);
      }
      __builtin_amdgcn_s_setprio(0);
    }
    // no trailing barrier: next phase's BAR A fences sB1/sK1; sK0's next
    // writer (phi0 by half0) follows its own wave's reads (in-order LDS).
  }

  // den: reduce dS over fr lanes; combine with denk via shfl
#pragma unroll
  for (int m2 = 1; m2 <= 8; m2 <<= 1) {
#pragma unroll
    for (int r = 0; r < 4; ++r) dS[r] += __shfl_xor(dS[r], m2, 64);
  }
  const int b = bh >> 4, hh = bh & 15;
#pragma unroll
  for (int r = 0; r < 4; ++r) {
    const float dk = __shfl(denk, fg * 4 + r, 64);   // token wl*16+fg*4+r
    const float rinv = 1.0f / (dk + dS[r] + 1e-6f);
    const int t = wl * 16 + fg * 4 + r;
    const int l = sc * 128 + h * 64 + t;
#pragma unroll
    for (int j = 0; j < 4; ++j) {
      const int d = j * 16 + fr;
      attn[((size_t)b * L_ + l) * DM_ + hh * 64 + d] = f2bf(oacc[j][r] * rinv);
    }
  }
}

extern "C" void kernel_launch(void* const* d_in, const int* in_sizes, int n_in,
                              void* d_out, int out_size, void* d_ws, size_t ws_size,
                              hipStream_t stream) {
  const float* x     = (const float*)d_in[0];
  const float* Wq    = (const float*)d_in[1];
  const float* bq    = (const float*)d_in[2];
  const float* Wk    = (const float*)d_in[3];
  const float* bk    = (const float*)d_in[4];
  const float* Wv    = (const float*)d_in[5];
  const float* bv    = (const float*)d_in[6];
  const float* Wo    = (const float*)d_in[7];
  const float* bo    = (const float*)d_in[8];
  const float* omega = (const float*)d_in[9];
  float* out = (float*)d_out;

  char* ws = (char*)d_ws;
  u16*   v      = (u16*)(ws);                           // 32 MB
  u16*   qb     = (u16*)(ws + 33554432ull);             // 32 MB
  u16*   kb     = (u16*)(ws + 67108864ull);             // 32 MB
  u16*   xb     = (u16*)(ws + 100663296ull);            // 32 MB (alias attn)
  u16*   attn   = xb;
  u16*   stateb = (u16*)(ws + 134217728ull);            // 64 MB
  float* ksum   = (float*)(ws + 201326592ull);          // 2 MB
  u16*   Wt     = (u16*)(ws + 203423744ull);            // 8 MB
  u16*   omb    = (u16*)(ws + 211812352ull);            // 32 KB -> 202 MB

  convx_k<<<16384, 256, 0, stream>>>(x, xb);
  convw_k<<<dim3(16, 16, 4), 256, 0, stream>>>(Wq, Wk, Wv, Wo, Wt);
  convom_k<<<64, 256, 0, stream>>>(omega, omb);

  mm_k<0><<<1024, 256, 0, stream>>>(xb, Wt,                 bq, qb);
  mm_k<0><<<1024, 256, 0, stream>>>(xb, Wt + 1048576ull,    bk, kb);
  mm_k<0><<<1024, 256, 0, stream>>>(xb, Wt + 2097152ull,    bv, v);
  kvstate_k<<<dim3(NSC, BH_), 256, 0, stream>>>(kb, v, omb, stateb, ksum);
  scan_k<<<dim3(8, BH_), 256, 0, stream>>>(stateb, ksum);
  outchunk_k<<<BH_ * NSC, 512, 0, stream>>>(qb, kb, v, omb, stateb, ksum, attn);
  mm_k<1><<<1024, 256, 0, stream>>>(attn, Wt + 3145728ull,  bo, out);
}

// Round 13
// 592.754 us; speedup vs baseline: 1.0813x; 1.0813x over previous
//
#include <hip/hip_runtime.h>
#include <hip/hip_bf16.h>

// FAVOR+ attention, MI355X. Round 13: revert mm_k to R11 (R12's global_load_lds
// geometry regressed: BK=32 doubled barriers + [row][32] LDS bank aliasing);
// outchunk: cross term fused into phi(q) loop (B-frag loads issued before phi,
// consumed after — latency hidden under phi compute; same-wave own-band
// sA write->read, no new barriers).
//  - kvstate / scan / convs: byte-identical to validated R11/R12.
//
// Workspace (bytes), total 211,845,120 (~202 MB):
//   v      bf16 [64bh][4096][64]   @ 0            (32 MB)
//   q      bf16                    @ 33,554,432   (32 MB)
//   k      bf16                    @ 67,108,864   (32 MB)
//   xb     bf16 [16384][1024]      @ 100,663,296  (32 MB) -- ALIASED attn
//   stateb bf16 [64bh][32][16384]  @ 134,217,728  (64 MB)
//   ksum   f32  [64bh][32][256]    @ 201,326,592  (2 MB)
//   Wt     bf16 4x[1024][1024]     @ 203,423,744  (8 MB)
//   omb    bf16 [256][64]          @ 211,812,352  (32 KB)

#define B_ 4
#define H_ 16
#define L_ 4096
#define D_ 64
#define M_ 256
#define DM_ 1024
#define BH_ 64
#define NSC 32            // superchunks per bh (SC = 128 tokens)

typedef unsigned int u32;
typedef unsigned short u16;
typedef __attribute__((ext_vector_type(8))) short bf16x8;
typedef __attribute__((ext_vector_type(4))) float f32x4;

static __device__ __forceinline__ float bf2f(u16 u) {
  return __uint_as_float(((u32)u) << 16);
}
static __device__ __forceinline__ u16 f2bf(float f) {
  u32 x = __float_as_uint(f);
  return (u16)((x + 0x7fffu + ((x >> 16) & 1u)) >> 16);   // RNE
}
#define MFMA16(a, b, c) __builtin_amdgcn_mfma_f32_16x16x32_bf16((a), (b), (c), 0, 0, 0)

// ---------------- converters ----------------------------------------------
__global__ __launch_bounds__(256) void convx_k(const float* __restrict__ x,
                                               u16* __restrict__ xb) {
  const int i = blockIdx.x * 256 + threadIdx.x;
  float4 f = ((const float4*)x)[i];
  ushort4 u;
  u.x = f2bf(f.x); u.y = f2bf(f.y); u.z = f2bf(f.z); u.w = f2bf(f.w);
  ((ushort4*)xb)[i] = u;
}

__global__ __launch_bounds__(256) void convw_k(
    const float* __restrict__ W0, const float* __restrict__ W1,
    const float* __restrict__ W2, const float* __restrict__ W3,
    u16* __restrict__ out) {
  __shared__ u16 tt[64][66];
  const int z = blockIdx.z;
  const float* W = (z == 0) ? W0 : (z == 1) ? W1 : (z == 2) ? W2 : W3;
  u16* o = out + (size_t)z * 1048576ull;
  const int k0 = blockIdx.y * 64, n0 = blockIdx.x * 64;
  const int r = threadIdx.x >> 4, c4 = (threadIdx.x & 15) << 2;
  for (int rr = r; rr < 64; rr += 16) {
    float4 w4 = *(const float4*)(W + (size_t)(k0 + rr) * DM_ + n0 + c4);
    tt[c4 + 0][rr] = f2bf(w4.x);
    tt[c4 + 1][rr] = f2bf(w4.y);
    tt[c4 + 2][rr] = f2bf(w4.z);
    tt[c4 + 3][rr] = f2bf(w4.w);
  }
  __syncthreads();
  for (int rr = r; rr < 64; rr += 16) {
    ushort4 u4;
    u4.x = tt[rr][c4 + 0];
    u4.y = tt[rr][c4 + 1];
    u4.z = tt[rr][c4 + 2];
    u4.w = tt[rr][c4 + 3];
    *(ushort4*)(o + (size_t)(n0 + rr) * DM_ + k0 + c4) = u4;
  }
}

__global__ __launch_bounds__(256) void convom_k(const float* __restrict__ om,
                                                u16* __restrict__ omb) {
  const int i = blockIdx.x * 256 + threadIdx.x;
  omb[i] = f2bf(om[i] * 0.35355339059327373f);       // fold 64^-0.25
}

// ---------------- bf16 MFMA GEMM, LDS-staged + XCD swizzle (R11-validated) --
template<int MODE>
__global__ __launch_bounds__(256) void mm_k(
    const u16* __restrict__ A, const u16* __restrict__ Bt,
    const float* __restrict__ bias, void* __restrict__ outp) {
  __shared__ u16 sA[128][64];   // 16 KB, XOR-swizzled 16B slots
  __shared__ u16 sB[128][64];   // 16 KB
  const int tid = threadIdx.x, lane = tid & 63, w = tid >> 6;
  const int fr = lane & 15, fg = lane >> 4;
  const int wr = w >> 1, wc = w & 1;
  const int lb = ((blockIdx.x & 7) << 7) | (blockIdx.x >> 3);
  const int m0 = (lb >> 3) * 128, n0 = (lb & 7) * 128;
  const int srow = tid >> 3, sslot = tid & 7;   // +p*32 rows per pass
  f32x4 acc[4][4] = {};
  bf16x8 av[4], bv[4];
#pragma unroll
  for (int p = 0; p < 4; ++p) {
    av[p] = *(const bf16x8*)(A  + (size_t)(m0 + srow + p * 32) * DM_ + sslot * 8);
    bv[p] = *(const bf16x8*)(Bt + (size_t)(n0 + srow + p * 32) * DM_ + sslot * 8);
  }
  for (int k0 = 0; k0 < DM_; k0 += 64) {
    __syncthreads();
#pragma unroll
    for (int p = 0; p < 4; ++p) {
      const int r = srow + p * 32;
      *(bf16x8*)&sA[r][(sslot ^ (r & 7)) * 8] = av[p];
      *(bf16x8*)&sB[r][(sslot ^ (r & 7)) * 8] = bv[p];
    }
    if (k0 + 64 < DM_) {
#pragma unroll
      for (int p = 0; p < 4; ++p) {
        av[p] = *(const bf16x8*)(A  + (size_t)(m0 + srow + p * 32) * DM_ + k0 + 64 + sslot * 8);
        bv[p] = *(const bf16x8*)(Bt + (size_t)(n0 + srow + p * 32) * DM_ + k0 + 64 + sslot * 8);
      }
    }
    __syncthreads();
#pragma unroll
    for (int ks = 0; ks < 2; ++ks) {
      bf16x8 af[4], bf[4];
#pragma unroll
      for (int i = 0; i < 4; ++i) {
        const int r = wr * 64 + i * 16 + fr;
        af[i] = *(const bf16x8*)&sA[r][((ks * 4 + fg) ^ (r & 7)) * 8];
      }
#pragma unroll
      for (int j = 0; j < 4; ++j) {
        const int r = wc * 64 + j * 16 + fr;
        bf[j] = *(const bf16x8*)&sB[r][((ks * 4 + fg) ^ (r & 7)) * 8];
      }
#pragma unroll
      for (int i = 0; i < 4; ++i)
#pragma unroll
        for (int j = 0; j < 4; ++j)
          acc[i][j] = MFMA16(af[i], bf[j], acc[i][j]);
    }
  }
  const int m_blk = m0 + wr * 64, n_blk = n0 + wc * 64;
#pragma unroll
  for (int j = 0; j < 4; ++j) {
    const int n = n_blk + j * 16 + fr;
    const float bi = bias[n];
    const int h = n >> 6, d = n & 63;
#pragma unroll
    for (int i = 0; i < 4; ++i) {
#pragma unroll
      for (int r = 0; r < 4; ++r) {
        const int m = m_blk + i * 16 + fg * 4 + r;
        const float val = acc[i][j][r] + bi;
        if (MODE == 0) {
          const int b = m >> 12, l = m & 4095;
          ((u16*)outp)[((size_t)(b * H_ + h) * L_ + l) * D_ + d] = f2bf(val);
        } else {
          ((float*)outp)[(size_t)m * DM_ + n] = val;
        }
      }
    }
  }
}

// ---------------- shared: LDS sumsq (kvstate, validated) -------------------
static __device__ __forceinline__ void sumsq_tile(
    const u16* __restrict__ xg, float (*ssq)[4], float* __restrict__ nh, int tid) {
  const int t = tid >> 2, qt = tid & 3;
  const u16* xp = xg + t * 64 + qt * 16;
  float s = 0.f;
#pragma unroll
  for (int jj = 0; jj < 2; ++jj) {
    bf16x8 xv = *(const bf16x8*)(xp + jj * 8);
#pragma unroll
    for (int e = 0; e < 8; ++e) { const float f = bf2f((u16)xv[e]); s += f * f; }
  }
  ssq[t][qt] = s;
  __syncthreads();
  if (tid < 64)
    nh[tid] = 0.0625f * (ssq[tid][0] + ssq[tid][1] + ssq[tid][2] + ssq[tid][3]);
  __syncthreads();
}

// ---------------- kvstate (MFMA, SC=128): bf16 state + f32 ksum ------------
__global__ __launch_bounds__(256) void kvstate_k(
    const u16* __restrict__ k, const u16* __restrict__ v,
    const u16* __restrict__ omb, u16* __restrict__ stateb,
    float* __restrict__ ksum) {
  __shared__ u16 sPhi[256][72];
  __shared__ u16 sVt[64][72];
  __shared__ float ssq[64][4];
  __shared__ float nh[64];
  const int tid = threadIdx.x, lane = tid & 63, w = tid >> 6;
  const int fr = lane & 15, fg = lane >> 4;
  const int sc = blockIdx.x, bh = blockIdx.y;
  const size_t base_l = (size_t)bh * L_ + (size_t)sc * 128;

  bf16x8 ones;
#pragma unroll
  for (int e = 0; e < 8; ++e) ones[e] = (short)0x3F80;

  f32x4 kvacc[4][4] = {};
  f32x4 ksacc[4] = {};

  for (int sub = 0; sub < 2; ++sub) {
    const size_t tl = base_l + sub * 64;
    const u16* kg = k + tl * 64;
    __syncthreads();
    {
      const u16* vp = v + (tl + lane) * 64 + w * 16;
      bf16x8 v0 = *(const bf16x8*)(vp);
      bf16x8 v1 = *(const bf16x8*)(vp + 8);
#pragma unroll
      for (int e = 0; e < 8; ++e) sVt[w * 16 + e][lane] = (u16)v0[e];
#pragma unroll
      for (int e = 0; e < 8; ++e) sVt[w * 16 + 8 + e][lane] = (u16)v1[e];
    }
    sumsq_tile(kg, ssq, nh, tid);
#pragma unroll
    for (int mi = 0; mi < 4; ++mi) {
      const int m0 = (w << 6) + mi * 16;
      const bf16x8 a0 = *(const bf16x8*)(omb + (m0 + fr) * 64 + fg * 8);
      const bf16x8 a1 = *(const bf16x8*)(omb + (m0 + fr) * 64 + 32 + fg * 8);
#pragma unroll
      for (int tt = 0; tt < 4; ++tt) {
        const bf16x8 b0 = *(const bf16x8*)(kg + (tt * 16 + fr) * 64 + fg * 8);
        const bf16x8 b1 = *(const bf16x8*)(kg + (tt * 16 + fr) * 64 + 32 + fg * 8);
        f32x4 acc = {0.f, 0.f, 0.f, 0.f};
        acc = MFMA16(a0, b0, acc);
        acc = MFMA16(a1, b1, acc);
        const float nhv = nh[tt * 16 + fr];
#pragma unroll
        for (int r = 0; r < 4; ++r)
          sPhi[m0 + fg * 4 + r][tt * 16 + fr] = f2bf(__expf(acc[r] - nhv) * 0.0625f);
      }
    }
    __syncthreads();
#pragma unroll
    for (int mi = 0; mi < 4; ++mi) {
      const int m0 = (w << 6) + mi * 16;
      const bf16x8 pb0 = *(const bf16x8*)&sPhi[m0 + fr][fg * 8];
      const bf16x8 pb1 = *(const bf16x8*)&sPhi[m0 + fr][32 + fg * 8];
      ksacc[mi] = MFMA16(pb0, ones, ksacc[mi]);
      ksacc[mi] = MFMA16(pb1, ones, ksacc[mi]);
#pragma unroll
      for (int dj = 0; dj < 4; ++dj) {
        const bf16x8 va0 = *(const bf16x8*)&sVt[dj * 16 + fr][fg * 8];
        const bf16x8 va1 = *(const bf16x8*)&sVt[dj * 16 + fr][32 + fg * 8];
        kvacc[mi][dj] = MFMA16(va0, pb0, kvacc[mi][dj]);
        kvacc[mi][dj] = MFMA16(va1, pb1, kvacc[mi][dj]);
      }
    }
  }
  // state bf16 [d][m]; ksum f32
  u16* stb = stateb + (size_t)(bh * NSC + sc) * (M_ * D_);
  float* ksp = ksum + (size_t)(bh * NSC + sc) * M_;
#pragma unroll
  for (int mi = 0; mi < 4; ++mi) {
    const int m = (w << 6) + mi * 16 + fr;
#pragma unroll
    for (int dj = 0; dj < 4; ++dj)
#pragma unroll
      for (int r = 0; r < 4; ++r)
        stb[(size_t)(dj * 16 + fg * 4 + r) * M_ + m] = f2bf(kvacc[mi][dj][r]);
    if (fr == 0) {
#pragma unroll
      for (int r = 0; r < 4; ++r)
        ksp[(w << 6) + mi * 16 + fg * 4 + r] = ksacc[mi][r];
    }
  }
}

// ---------------- exclusive prefix over superchunks (bf16 state) -----------
__global__ __launch_bounds__(256) void scan_k(u16* __restrict__ stateb,
                                              float* __restrict__ ksum) {
  const int bh = blockIdx.y;
  u16* sb = stateb + (size_t)bh * NSC * (M_ * D_);
  const int base = blockIdx.x * 2048 + threadIdx.x * 8;
  float run[8] = {};
  for (int cc = 0; cc < NSC; ++cc) {
    u16* st = sb + (size_t)cc * (M_ * D_) + base;
    ushort4 t0 = *(ushort4*)st;
    ushort4 t1 = *(ushort4*)(st + 4);
    ushort4 w0, w1;
    w0.x = f2bf(run[0]); w0.y = f2bf(run[1]); w0.z = f2bf(run[2]); w0.w = f2bf(run[3]);
    w1.x = f2bf(run[4]); w1.y = f2bf(run[5]); w1.z = f2bf(run[6]); w1.w = f2bf(run[7]);
    *(ushort4*)st = w0;
    *(ushort4*)(st + 4) = w1;
    run[0] += bf2f(t0.x); run[1] += bf2f(t0.y); run[2] += bf2f(t0.z); run[3] += bf2f(t0.w);
    run[4] += bf2f(t1.x); run[5] += bf2f(t1.y); run[6] += bf2f(t1.z); run[7] += bf2f(t1.w);
  }
  if (blockIdx.x == 0) {           // ksum f32 in-place exclusive prefix
    float rk = 0.f;
    for (int cc = 0; cc < NSC; ++cc) {
      float* p = ksum + (size_t)(bh * NSC + cc) * M_ + threadIdx.x;
      const float t = *p;
      *p = rk;
      rk += t;
    }
  }
}

// ---------------- outchunk helpers (validated) -----------------------------
// per-wave sumsq via shfl; band index wb in [0,4)
static __device__ __forceinline__ void sumsq_wave(
    const u16* __restrict__ xg, int wb, int lane, float* nhv) {
  const u16* xp = xg + (wb * 16 + (lane & 15)) * 64;
  float s = 0.f;
#pragma unroll
  for (int p = 0; p < 8; ++p) {
    bf16x8 xv = *(const bf16x8*)(xp + p * 8);
#pragma unroll
    for (int e = 0; e < 8; ++e) { const float f = bf2f((u16)xv[e]); s += f * f; }
  }
  s *= 0.0625f;
  const int fg = lane >> 4;
#pragma unroll
  for (int r = 0; r < 4; ++r) nhv[r] = __shfl(s, fg * 4 + r, 64);
}

// phi quadrant: writes ONLY rows of band wb (wb*16..wb*16+15)
static __device__ __forceinline__ void phi_quad(
    const u16* __restrict__ xg, const u16* __restrict__ ombq,
    u16* __restrict__ dst, int dstride, const float* nhv,
    int wb, int lane) {
  const int fr = lane & 15, fg = lane >> 4;
  const int tband = wb * 16;
  const bf16x8 a0 = *(const bf16x8*)(xg + (tband + fr) * 64 + fg * 8);
  const bf16x8 a1 = *(const bf16x8*)(xg + (tband + fr) * 64 + 32 + fg * 8);
#pragma unroll
  for (int j = 0; j < 4; ++j) {
    const bf16x8 b0 = *(const bf16x8*)(ombq + (j * 16 + fr) * 64 + fg * 8);
    const bf16x8 b1 = *(const bf16x8*)(ombq + (j * 16 + fr) * 64 + 32 + fg * 8);
    f32x4 acc = {0.f, 0.f, 0.f, 0.f};
    acc = MFMA16(a0, b0, acc);
    acc = MFMA16(a1, b1, acc);
#pragma unroll
    for (int r = 0; r < 4; ++r) {
      const int t = tband + fg * 4 + r;
      dst[t * dstride + j * 16 + fr] = f2bf(__expf(acc[r] - nhv[r]) * 0.0625f);
    }
  }
}

// ---------------- outchunk: merged superchunk, fused phi(q)+cross ----------
__global__ __launch_bounds__(512) void outchunk_k(
    const u16* __restrict__ q, const u16* __restrict__ kk,
    const u16* __restrict__ v, const u16* __restrict__ omb,
    const u16* __restrict__ stateb, const float* __restrict__ ksum,
    u16* __restrict__ attn) {
  __shared__ u16 sA[2][64][264];  // Qp per half            67,584 B
  __shared__ u16 sK0[64][72];     // phi(k) ping / h0 S      9,216 B
  __shared__ u16 sK1[64][72];     // phi(k) pong / h1 S      9,216 B
  __shared__ u16 sB1[64][72];     // vT                      9,216 B
  __shared__ float ksum_l[256];   //  1,024 B   total 96,256 B -> 1/CU
  const int tid = threadIdx.x, lane = tid & 63, w = tid >> 6;
  const int h = w >> 2, wl = w & 3;
  const int fr = lane & 15, fg = lane >> 4;
  const int bh = blockIdx.x >> 5, sc = blockIdx.x & 31;
  const size_t tokq = (size_t)bh * L_ + (size_t)sc * 128 + (size_t)h * 64;
  const u16* qg = q + tokq * 64;
  const u16* stgb = stateb + (size_t)(bh * NSC + sc) * (M_ * D_);   // [d][m]
  const float* ksg = ksum + (size_t)(bh * NSC + sc) * M_;

  if (tid < 256) ksum_l[tid] = ksg[tid];

  float nhq[4];
  sumsq_wave(qg, wl, lane, nhq);

  // fused phi(q) + cross term: per quadrant, issue state B-frag loads FIRST
  // (latency hidden under phi compute), phi(q)->sA[h] own band, then cross
  // MFMAs reading the just-written own-band rows (same-wave in-order LDS).
  f32x4 oacc[4] = {};
#pragma unroll 1
  for (int mq = 0; mq < 4; ++mq) {
    bf16x8 b0r[4], b1r[4];
#pragma unroll
    for (int j = 0; j < 4; ++j) {
      b0r[j] = *(const bf16x8*)(stgb + (size_t)(j * 16 + fr) * M_ + mq * 64 + fg * 8);
      b1r[j] = *(const bf16x8*)(stgb + (size_t)(j * 16 + fr) * M_ + mq * 64 + 32 + fg * 8);
    }
    phi_quad(qg, omb + mq * 4096, &sA[h][0][mq * 64], 264, nhq, wl, lane);
    const bf16x8 a0 = *(const bf16x8*)&sA[h][wl * 16 + fr][mq * 64 + fg * 8];
    const bf16x8 a1 = *(const bf16x8*)&sA[h][wl * 16 + fr][mq * 64 + 32 + fg * 8];
    __builtin_amdgcn_s_setprio(1);
#pragma unroll
    for (int j = 0; j < 4; ++j) {
      oacc[j] = MFMA16(a0, b0r[j], oacc[j]);
      oacc[j] = MFMA16(a1, b1r[j], oacc[j]);
    }
    __builtin_amdgcn_s_setprio(0);
  }
  __syncthreads();   // BAR P: ksum_l visibility (sA only ever read own-band)

  // den-ksum: lane (fr,fg) -> token wl*16+fr, m-quarter fg; reduce over fg.
  float denk = 0.f;
#pragma unroll
  for (int g8 = 0; g8 < 8; ++g8) {
    bf16x8 qv = *(const bf16x8*)&sA[h][wl * 16 + fr][fg * 64 + g8 * 8];
#pragma unroll
    for (int e = 0; e < 8; ++e)
      denk += bf2f((u16)qv[e]) * ksum_l[fg * 64 + g8 * 8 + e];
  }
  denk += __shfl_xor(denk, 16, 64);
  denk += __shfl_xor(denk, 32, 64);

  // ---- source chunks s=0,1. phi(k) quadrant mq produced by half (mq&1);
  //      half0 participates in S/SV only at s=0; diag mask when s==h.
  float dS[4] = {0.f, 0.f, 0.f, 0.f};
#pragma unroll 1
  for (int s = 0; s < 2; ++s) {
    const size_t ktok = (size_t)bh * L_ + (size_t)sc * 128 + (size_t)s * 64;
    const u16* kg = kk + ktok * 64;
    const bool part = (h == 1) || (s == 0);
    const bool diag = (s == h);
    float nhk[4];
    sumsq_wave(kg, wl, lane, nhk);
    f32x4 sacc[4] = {};
    if (h == 0)   // quadrant 0 producer (sK0 WAR: prior reads were same-wave)
      phi_quad(kg, omb, &sK0[0][0], 72, nhk, wl, lane);
    __syncthreads();   // BAR A: quadrant 0 ready; fences prev-phase sB1/sK1 readers
#pragma unroll 1
    for (int mq = 0; mq < 4; ++mq) {
      u16* nxt = ((mq & 1) == 0) ? &sK1[0][0] : &sK0[0][0];
      const u16 (*cur)[72] = ((mq & 1) == 0) ? sK0 : sK1;
      if (mq < 3 && h == ((mq + 1) & 1))
        phi_quad(kg, omb + (mq + 1) * 4096, nxt, 72, nhk, wl, lane);
      if (part) {
        const bf16x8 a0 = *(const bf16x8*)&sA[h][wl * 16 + fr][mq * 64 + fg * 8];
        const bf16x8 a1 = *(const bf16x8*)&sA[h][wl * 16 + fr][mq * 64 + 32 + fg * 8];
        __builtin_amdgcn_s_setprio(1);
#pragma unroll
        for (int j = 0; j < 4; ++j) {
          const bf16x8 b0 = *(const bf16x8*)&cur[j * 16 + fr][fg * 8];
          const bf16x8 b1 = *(const bf16x8*)&cur[j * 16 + fr][32 + fg * 8];
          sacc[j] = MFMA16(a0, b0, sacc[j]);
          sacc[j] = MFMA16(a1, b1, sacc[j]);
        }
        __builtin_amdgcn_s_setprio(0);
      }
      __syncthreads();   // quadrant BAR: nxt ready / WAR fence on cur
    }
    // S write (half h into its own buffer; own-band rows), dS from rounded val
    u16 (*sS)[72] = (h == 0) ? sK0 : sK1;
    if (part) {
#pragma unroll
      for (int j = 0; j < 4; ++j)
#pragma unroll
        for (int r = 0; r < 4; ++r) {
          const int ss = j * 16 + fr, t = wl * 16 + fg * 4 + r;
          float val = sacc[j][r];
          if (diag && ss > t) val = 0.f;
          const u16 vb = f2bf(val);
          sS[t][ss] = vb;
          dS[r] += bf2f(vb);
        }
    }
    if (h == 0) {  // vT staging (bands wl*16; prior readers fenced by BAR A)
      const u16* vp = v + (ktok + lane) * 64 + wl * 16;
      bf16x8 v0 = *(const bf16x8*)(vp);
      bf16x8 v1 = *(const bf16x8*)(vp + 8);
#pragma unroll
      for (int e = 0; e < 8; ++e) sB1[wl * 16 + e][lane] = (u16)v0[e];
#pragma unroll
      for (int e = 0; e < 8; ++e) sB1[wl * 16 + 8 + e][lane] = (u16)v1[e];
    }
    __syncthreads();   // BAR F: S buffers + vT visible
    if (part) {        // S @ V (A: own buffer own band; B: sB1 cross-band)
      const bf16x8 a0 = *(const bf16x8*)&sS[wl * 16 + fr][fg * 8];
      const bf16x8 a1 = *(const bf16x8*)&sS[wl * 16 + fr][32 + fg * 8];
      __builtin_amdgcn_s_setprio(1);
#pragma unroll
      for (int j = 0; j < 4; ++j) {
        const bf16x8 b0 = *(const bf16x8*)&sB1[j * 16 + fr][fg * 8];
        const bf16x8 b1 = *(const bf16x8*)&sB1[j * 16 + fr][32 + fg * 8];
        oacc[j] = MFMA16(a0, b0, oacc[j]);
        oacc[j] = MFMA16(a1, b1, oacc[j]);
      }
      __builtin_amdgcn_s_setprio(0);
    }
    // no trailing barrier: next phase's BAR A fences sB1/sK1; sK0's next
    // writer (phi0 by half0) follows its own wave's reads (in-order LDS).
  }

  // den: reduce dS over fr lanes; combine with denk via shfl
#pragma unroll
  for (int m2 = 1; m2 <= 8; m2 <<= 1) {
#pragma unroll
    for (int r = 0; r < 4; ++r) dS[r] += __shfl_xor(dS[r], m2, 64);
  }
  const int b = bh >> 4, hh = bh & 15;
#pragma unroll
  for (int r = 0; r < 4; ++r) {
    const float dk = __shfl(denk, fg * 4 + r, 64);   // token wl*16+fg*4+r
    const float rinv = 1.0f / (dk + dS[r] + 1e-6f);
    const int t = wl * 16 + fg * 4 + r;
    const int l = sc * 128 + h * 64 + t;
#pragma unroll
    for (int j = 0; j < 4; ++j) {
      const int d = j * 16 + fr;
      attn[((size_t)b * L_ + l) * DM_ + hh * 64 + d] = f2bf(oacc[j][r] * rinv);
    }
  }
}

extern "C" void kernel_launch(void* const* d_in, const int* in_sizes, int n_in,
                              void* d_out, int out_size, void* d_ws, size_t ws_size,
                              hipStream_t stream) {
  const float* x     = (const float*)d_in[0];
  const float* Wq    = (const float*)d_in[1];
  const float* bq    = (const float*)d_in[2];
  const float* Wk    = (const float*)d_in[3];
  const float* bk    = (const float*)d_in[4];
  const float* Wv    = (const float*)d_in[5];
  const float* bv    = (const float*)d_in[6];
  const float* Wo    = (const float*)d_in[7];
  const float* bo    = (const float*)d_in[8];
  const float* omega = (const float*)d_in[9];
  float* out = (float*)d_out;

  char* ws = (char*)d_ws;
  u16*   v      = (u16*)(ws);                           // 32 MB
  u16*   qb     = (u16*)(ws + 33554432ull);             // 32 MB
  u16*   kb     = (u16*)(ws + 67108864ull);             // 32 MB
  u16*   xb     = (u16*)(ws + 100663296ull);            // 32 MB (alias attn)
  u16*   attn   = xb;
  u16*   stateb = (u16*)(ws + 134217728ull);            // 64 MB
  float* ksum   = (float*)(ws + 201326592ull);          // 2 MB
  u16*   Wt     = (u16*)(ws + 203423744ull);            // 8 MB
  u16*   omb    = (u16*)(ws + 211812352ull);            // 32 KB -> 202 MB

  convx_k<<<16384, 256, 0, stream>>>(x, xb);
  convw_k<<<dim3(16, 16, 4), 256, 0, stream>>>(Wq, Wk, Wv, Wo, Wt);
  convom_k<<<64, 256, 0, stream>>>(omega, omb);

  mm_k<0><<<1024, 256, 0, stream>>>(xb, Wt,                 bq, qb);
  mm_k<0><<<1024, 256, 0, stream>>>(xb, Wt + 1048576ull,    bk, kb);
  mm_k<0><<<1024, 256, 0, stream>>>(xb, Wt + 2097152ull,    bv, v);
  kvstate_k<<<dim3(NSC, BH_), 256, 0, stream>>>(kb, v, omb, stateb, ksum);
  scan_k<<<dim3(8, BH_), 256, 0, stream>>>(stateb, ksum);
  outchunk_k<<<BH_ * NSC, 512, 0, stream>>>(qb, kb, v, omb, stateb, ksum, attn);
  mm_k<1><<<1024, 256, 0, stream>>>(attn, Wt + 3145728ull,  bo, out);
}